// Round 1
// baseline (1156.419 us; speedup 1.0000x reference)
//
#include <hip/hip_runtime.h>

#define HC 256      // HEADS*HID
#define HEADS 8
#define HID 32
#define GRAPHS 512
#define NEG_SLOPE 0.2f

// ------------------------------------------------------------------
// int32/int64 index handling (JAX may emit either for edge_index/batch)
__device__ __forceinline__ int IDX(const void* p, long long i, int mode) {
    if (mode) return (int)((const long long*)p)[i];
    return ((const int*)p)[i];
}

__global__ void detect_kernel(const unsigned int* __restrict__ words, int* __restrict__ mode, int e) {
    // If data is int64 (values < 2^31), every odd 32-bit word of the first
    // 4096 elements is 0. If int32, those words are random edge values.
    __shared__ unsigned int red[256];
    unsigned int v = 0;
    int lim = e < 4096 ? e : 4096;
    for (int i = threadIdx.x; i < lim; i += 256) v |= words[2 * i + 1];
    red[threadIdx.x] = v;
    __syncthreads();
    for (int off = 128; off > 0; off >>= 1) {
        if (threadIdx.x < off) red[threadIdx.x] |= red[threadIdx.x + off];
        __syncthreads();
    }
    if (threadIdx.x == 0) *mode = (red[0] == 0u) ? 1 : 0;  // 1 => int64
}

// ------------------------------------------------------------------
// CSR build: histogram -> scan -> scatter
__global__ void hist_kernel(const void* __restrict__ edge, const int* __restrict__ mode,
                            int* __restrict__ hist, int e) {
    int m = mode[0];
    int i = blockIdx.x * blockDim.x + threadIdx.x;
    if (i < e) atomicAdd(&hist[IDX(edge, (long long)e + i, m)], 1);
}

__global__ void scan1(const int* __restrict__ hist, int* __restrict__ excl,
                      int* __restrict__ bsum, int n) {
    __shared__ int buf[256];
    int i = blockIdx.x * 256 + threadIdx.x;
    int v = (i < n) ? hist[i] : 0;
    buf[threadIdx.x] = v;
    __syncthreads();
    for (int off = 1; off < 256; off <<= 1) {
        int t = (threadIdx.x >= (unsigned)off) ? buf[threadIdx.x - off] : 0;
        __syncthreads();
        buf[threadIdx.x] += t;
        __syncthreads();
    }
    if (i < n) excl[i] = buf[threadIdx.x] - v;
    if (threadIdx.x == 255) bsum[blockIdx.x] = buf[255];
}

__global__ void scan2(int* __restrict__ bsum, int nb) {
    __shared__ int buf[256];
    int v = (threadIdx.x < (unsigned)nb) ? bsum[threadIdx.x] : 0;
    buf[threadIdx.x] = v;
    __syncthreads();
    for (int off = 1; off < 256; off <<= 1) {
        int t = (threadIdx.x >= (unsigned)off) ? buf[threadIdx.x - off] : 0;
        __syncthreads();
        buf[threadIdx.x] += t;
        __syncthreads();
    }
    if (threadIdx.x < (unsigned)nb) bsum[threadIdx.x] = buf[threadIdx.x] - v;  // exclusive
}

__global__ void scan3(int* __restrict__ row_ptr, const int* __restrict__ bsum, int n, int e) {
    int i = blockIdx.x * 256 + threadIdx.x;
    if (i < n) row_ptr[i] += bsum[i >> 8];
    if (i == 0) row_ptr[n] = e;
}

__global__ void scatter_kernel(const void* __restrict__ edge, const int* __restrict__ mode,
                               const int* __restrict__ row_ptr, int* __restrict__ fill,
                               int* __restrict__ out, int e) {
    int m = mode[0];
    int i = blockIdx.x * blockDim.x + threadIdx.x;
    if (i < e) {
        int d = IDX(edge, (long long)e + i, m);
        int pos = row_ptr[d] + atomicAdd(&fill[d], 1);
        out[pos] = IDX(edge, (long long)i, m);
    }
}

// ------------------------------------------------------------------
// fp32 GEMM: C[M,256] = A[M,K] @ B[K,256], tiles 64x64, BK=16
__global__ __launch_bounds__(256) void gemm64(const float* __restrict__ A,
                                              const float* __restrict__ B,
                                              float* __restrict__ C, int M, int K) {
    __shared__ float As[16][64];
    __shared__ float Bs[16][64];
    const int tid = threadIdx.x;
    const int tx = tid & 15, ty = tid >> 4;
    const int row0 = blockIdx.x * 64, col0 = blockIdx.y * 64;
    float acc[4][4] = {};
    for (int k0 = 0; k0 < K; k0 += 16) {
        for (int e = tid; e < 64 * 16; e += 256) {
            int r = e & 63, kk = e >> 6;                  // conflict-free LDS write
            As[kk][r] = (row0 + r < M) ? A[(size_t)(row0 + r) * K + k0 + kk] : 0.f;
        }
        for (int e = tid; e < 16 * 64; e += 256) {
            int kk = e >> 6, c = e & 63;                  // coalesced global, linear LDS
            Bs[kk][c] = B[(size_t)(k0 + kk) * HC + col0 + c];
        }
        __syncthreads();
#pragma unroll
        for (int kk = 0; kk < 16; ++kk) {
            float4 a = *(const float4*)&As[kk][ty * 4];
            float4 b = *(const float4*)&Bs[kk][tx * 4];
            float av[4] = {a.x, a.y, a.z, a.w};
            float bv[4] = {b.x, b.y, b.z, b.w};
#pragma unroll
            for (int i = 0; i < 4; ++i)
#pragma unroll
                for (int j = 0; j < 4; ++j) acc[i][j] = fmaf(av[i], bv[j], acc[i][j]);
        }
        __syncthreads();
    }
#pragma unroll
    for (int i = 0; i < 4; ++i) {
        int r = row0 + ty * 4 + i;
        if (r < M) {
            float4 o = make_float4(acc[i][0], acc[i][1], acc[i][2], acc[i][3]);
            *(float4*)&C[(size_t)r * HC + col0 + tx * 4] = o;
        }
    }
}

// ------------------------------------------------------------------
// per-node attention logits: asrc[n,h] = <h[n,h,:], a_src[h,:]>, same for adst
__global__ void alpha_kernel(const float* __restrict__ h, const float* __restrict__ a_src,
                             const float* __restrict__ a_dst, float* __restrict__ asrc,
                             float* __restrict__ adst, int n) {
    int t = blockIdx.x * blockDim.x + threadIdx.x;
    if (t >= n * HEADS) return;
    int node = t >> 3, head = t & 7;
    const float4* hp = (const float4*)(h + (size_t)node * HC + head * HID);
    const float4* w1 = (const float4*)(a_src + head * HID);
    const float4* w2 = (const float4*)(a_dst + head * HID);
    float s1 = 0.f, s2 = 0.f;
#pragma unroll
    for (int q = 0; q < 8; ++q) {
        float4 hv = hp[q], a1 = w1[q], a2 = w2[q];
        s1 += hv.x * a1.x + hv.y * a1.y + hv.z * a1.z + hv.w * a1.w;
        s2 += hv.x * a2.x + hv.y * a2.y + hv.z * a2.z + hv.w * a2.w;
    }
    asrc[t] = s1;
    adst[t] = s2;
}

// ------------------------------------------------------------------
// one wave per dst node: online-softmax over in-edges (+self-loop), 4 ch/lane
__global__ __launch_bounds__(256) void gat_aggregate(
    const float* __restrict__ h, const float* __restrict__ asrc,
    const float* __restrict__ adst, const int* __restrict__ row_ptr,
    const int* __restrict__ srcs, const float* __restrict__ bias,
    float* __restrict__ out, int n) {
    int node = (blockIdx.x * blockDim.x + threadIdx.x) >> 6;
    int lane = threadIdx.x & 63;
    if (node >= n) return;
    int head = lane >> 3;   // 4 channels/lane stay within one head
    int c0 = lane * 4;
    float ad = adst[node * HEADS + head];
    float e0 = asrc[node * HEADS + head] + ad;
    e0 = e0 > 0.f ? e0 : NEG_SLOPE * e0;
    float m = e0, denom = 1.f;
    float4 acc = *(const float4*)(h + (size_t)node * HC + c0);   // self-loop, weight exp(0)=1
    int beg = row_ptr[node], end = row_ptr[node + 1];
    for (int j = beg; j < end; ++j) {
        int s = srcs[j];
        float as = asrc[s * HEADS + head];
        float ee = as + ad;
        ee = ee > 0.f ? ee : NEG_SLOPE * ee;
        float nm = fmaxf(m, ee);
        float sc = __expf(m - nm);
        float p = __expf(ee - nm);
        float4 hv = *(const float4*)(h + (size_t)s * HC + c0);
        denom = denom * sc + p;
        acc.x = fmaf(acc.x, sc, p * hv.x);
        acc.y = fmaf(acc.y, sc, p * hv.y);
        acc.z = fmaf(acc.z, sc, p * hv.z);
        acc.w = fmaf(acc.w, sc, p * hv.w);
        m = nm;
    }
    float inv = 1.f / (denom + 1e-16f);
    float4 b = *(const float4*)(bias + c0);
    float o[4] = {fmaf(acc.x, inv, b.x), fmaf(acc.y, inv, b.y),
                  fmaf(acc.z, inv, b.z), fmaf(acc.w, inv, b.w)};
#pragma unroll
    for (int q = 0; q < 4; ++q) o[q] = o[q] > 0.f ? o[q] : __expf(o[q]) - 1.f;  // ELU
    *(float4*)(out + (size_t)node * HC + c0) = make_float4(o[0], o[1], o[2], o[3]);
}

// ------------------------------------------------------------------
__global__ void pool_kernel(const float* __restrict__ hf, const void* __restrict__ batch,
                            const int* __restrict__ mode, float* __restrict__ pooled,
                            float* __restrict__ cnts, int n) {
    int node = (blockIdx.x * blockDim.x + threadIdx.x) >> 6;
    int lane = threadIdx.x & 63;
    if (node >= n) return;
    int m = mode[0];
    int g = IDX(batch, node, m);
    float4 hv = *(const float4*)(hf + (size_t)node * HC + lane * 4);
    float* p = pooled + (size_t)g * HC + lane * 4;
    atomicAdd(p + 0, hv.x);
    atomicAdd(p + 1, hv.y);
    atomicAdd(p + 2, hv.z);
    atomicAdd(p + 3, hv.w);
    if (lane == 0) atomicAdd(&cnts[g], 1.f);
}

__global__ void final_kernel(const float* __restrict__ pooled, const float* __restrict__ cnts,
                             const float* __restrict__ lin_w, const float* __restrict__ lin_b,
                             float* __restrict__ outp) {
    int g = (blockIdx.x * blockDim.x + threadIdx.x) >> 6;
    int lane = threadIdx.x & 63;
    if (g >= GRAPHS) return;
    float4 pv = *(const float4*)(pooled + (size_t)g * HC + lane * 4);
    float4 wv = *(const float4*)(lin_w + lane * 4);
    float s = pv.x * wv.x + pv.y * wv.y + pv.z * wv.z + pv.w * wv.w;
    for (int off = 32; off > 0; off >>= 1) s += __shfl_down(s, off, 64);
    if (lane == 0) {
        float c = cnts[g];
        c = c > 1.f ? c : 1.f;
        outp[g] = s / c + lin_b[0];
    }
}

// ------------------------------------------------------------------
extern "C" void kernel_launch(void* const* d_in, const int* in_sizes, int n_in,
                              void* d_out, int out_size, void* d_ws, size_t ws_size,
                              hipStream_t stream) {
    const float* x = (const float*)d_in[0];
    const void* edge = d_in[1];
    const void* batch = d_in[2];
    const float* W[3]    = {(const float*)d_in[3], (const float*)d_in[7],  (const float*)d_in[11]};
    const float* ASRC[3] = {(const float*)d_in[4], (const float*)d_in[8],  (const float*)d_in[12]};
    const float* ADST[3] = {(const float*)d_in[5], (const float*)d_in[9],  (const float*)d_in[13]};
    const float* BIAS[3] = {(const float*)d_in[6], (const float*)d_in[10], (const float*)d_in[14]};
    const float* lin_w = (const float*)d_in[15];
    const float* lin_b = (const float*)d_in[16];
    float* outp = (float*)d_out;

    const int n = in_sizes[0] / 128;  // 50000
    const int e = in_sizes[1] / 2;    // 800000
    const int IN_CH = 128;

    char* ws = (char*)d_ws;
    size_t off = 0;
    auto alloc = [&](size_t bytes) -> void* {
        void* p = ws + off;
        off = (off + bytes + 255) & ~(size_t)255;
        return p;
    };
    float* hbuf   = (float*)alloc((size_t)n * HC * 4);
    float* gbuf   = (float*)alloc((size_t)n * HC * 4);
    float* as_buf = (float*)alloc((size_t)n * HEADS * 4);
    float* ad_buf = (float*)alloc((size_t)n * HEADS * 4);
    int* hist     = (int*)alloc((size_t)n * 4);          // reused as fill
    int* row_ptr  = (int*)alloc((size_t)(n + 1) * 4);
    int* bsum     = (int*)alloc(1024);
    int* mode     = (int*)alloc(256);
    int* srcs     = (int*)alloc((size_t)e * 4);
    float* pooled = (float*)alloc((size_t)GRAPHS * HC * 4);
    float* cnts   = (float*)alloc((size_t)GRAPHS * 4);
    if (off > ws_size) return;  // workspace too small — would fail loudly

    const int nb = (n + 255) / 256;

    detect_kernel<<<1, 256, 0, stream>>>((const unsigned int*)edge, mode, e);

    // CSR build
    hipMemsetAsync(hist, 0, (size_t)n * 4, stream);
    hist_kernel<<<(e + 255) / 256, 256, 0, stream>>>(edge, mode, hist, e);
    scan1<<<nb, 256, 0, stream>>>(hist, row_ptr, bsum, n);
    scan2<<<1, 256, 0, stream>>>(bsum, nb);
    scan3<<<nb, 256, 0, stream>>>(row_ptr, bsum, n, e);
    hipMemsetAsync(hist, 0, (size_t)n * 4, stream);
    scatter_kernel<<<(e + 255) / 256, 256, 0, stream>>>(edge, mode, row_ptr, hist, srcs, e);

    hipMemsetAsync(pooled, 0, (size_t)GRAPHS * HC * 4, stream);
    hipMemsetAsync(cnts, 0, (size_t)GRAPHS * 4, stream);

    dim3 gemm_grid((n + 63) / 64, 4);
    const float* cur_in = x;
    int K = IN_CH;
    for (int l = 0; l < 3; ++l) {
        gemm64<<<gemm_grid, 256, 0, stream>>>(cur_in, W[l], hbuf, n, K);
        alpha_kernel<<<(n * HEADS + 255) / 256, 256, 0, stream>>>(hbuf, ASRC[l], ADST[l],
                                                                  as_buf, ad_buf, n);
        gat_aggregate<<<(n + 3) / 4, 256, 0, stream>>>(hbuf, as_buf, ad_buf, row_ptr, srcs,
                                                       BIAS[l], gbuf, n);
        cur_in = gbuf;
        K = HC;
    }

    pool_kernel<<<(n + 3) / 4, 256, 0, stream>>>(gbuf, batch, mode, pooled, cnts, n);
    final_kernel<<<(GRAPHS + 3) / 4, 256, 0, stream>>>(pooled, cnts, lin_w, lin_b, outp);
}

// Round 2
// 911.456 us; speedup vs baseline: 1.2688x; 1.2688x over previous
//
#include <hip/hip_runtime.h>

#define HC 256      // HEADS*HID
#define HEADS 8
#define HID 32
#define GRAPHS 512
#define NEG_SLOPE 0.2f

// ------------------------------------------------------------------
// int32/int64 index handling (JAX may emit either for edge_index/batch)
__device__ __forceinline__ int IDX(const void* p, long long i, int mode) {
    if (mode) return (int)((const long long*)p)[i];
    return ((const int*)p)[i];
}

__global__ void detect_kernel(const unsigned int* __restrict__ words, int* __restrict__ mode, int e) {
    __shared__ unsigned int red[256];
    unsigned int v = 0;
    int lim = e < 4096 ? e : 4096;
    for (int i = threadIdx.x; i < lim; i += 256) v |= words[2 * i + 1];
    red[threadIdx.x] = v;
    __syncthreads();
    for (int off = 128; off > 0; off >>= 1) {
        if (threadIdx.x < off) red[threadIdx.x] |= red[threadIdx.x + off];
        __syncthreads();
    }
    if (threadIdx.x == 0) *mode = (red[0] == 0u) ? 1 : 0;  // 1 => int64
}

// ------------------------------------------------------------------
// CSR build: histogram -> scan -> scatter
__global__ void hist_kernel(const void* __restrict__ edge, const int* __restrict__ mode,
                            int* __restrict__ hist, int e) {
    int m = mode[0];
    int i = blockIdx.x * blockDim.x + threadIdx.x;
    if (i < e) atomicAdd(&hist[IDX(edge, (long long)e + i, m)], 1);
}

__global__ void scan1(const int* __restrict__ hist, int* __restrict__ excl,
                      int* __restrict__ bsum, int n) {
    __shared__ int buf[256];
    int i = blockIdx.x * 256 + threadIdx.x;
    int v = (i < n) ? hist[i] : 0;
    buf[threadIdx.x] = v;
    __syncthreads();
    for (int off = 1; off < 256; off <<= 1) {
        int t = (threadIdx.x >= (unsigned)off) ? buf[threadIdx.x - off] : 0;
        __syncthreads();
        buf[threadIdx.x] += t;
        __syncthreads();
    }
    if (i < n) excl[i] = buf[threadIdx.x] - v;
    if (threadIdx.x == 255) bsum[blockIdx.x] = buf[255];
}

__global__ void scan2(int* __restrict__ bsum, int nb) {
    __shared__ int buf[256];
    int v = (threadIdx.x < (unsigned)nb) ? bsum[threadIdx.x] : 0;
    buf[threadIdx.x] = v;
    __syncthreads();
    for (int off = 1; off < 256; off <<= 1) {
        int t = (threadIdx.x >= (unsigned)off) ? buf[threadIdx.x - off] : 0;
        __syncthreads();
        buf[threadIdx.x] += t;
        __syncthreads();
    }
    if (threadIdx.x < (unsigned)nb) bsum[threadIdx.x] = buf[threadIdx.x] - v;  // exclusive
}

__global__ void scan3(int* __restrict__ row_ptr, const int* __restrict__ bsum, int n, int e) {
    int i = blockIdx.x * 256 + threadIdx.x;
    if (i < n) row_ptr[i] += bsum[i >> 8];
    if (i == 0) row_ptr[n] = e;
}

__global__ void scatter_kernel(const void* __restrict__ edge, const int* __restrict__ mode,
                               const int* __restrict__ row_ptr, int* __restrict__ fill,
                               int* __restrict__ out, int e) {
    int m = mode[0];
    int i = blockIdx.x * blockDim.x + threadIdx.x;
    if (i < e) {
        int d = IDX(edge, (long long)e + i, m);
        int pos = row_ptr[d] + atomicAdd(&fill[d], 1);
        out[pos] = IDX(edge, (long long)i, m);
    }
}

// ------------------------------------------------------------------
// fp32 GEMM: C[M,256] = A[M,K] @ B[K,256], tile 128x128, 8x8 micro (4+4 split)
__device__ __forceinline__ int bswz(int b) { return b ^ ((b >> 3) & 3); }  // involution

__global__ __launch_bounds__(256) void gemm128(const float* __restrict__ A,
                                               const float* __restrict__ B,
                                               float* __restrict__ C, int M, int K) {
    __shared__ float As[16][132];       // +4 pad: transpose-write 2-way max
    __shared__ float Bs[16 * 128];      // XOR-swizzled blocks of 4 floats
    const int tid = threadIdx.x;
    const int tx = tid & 15, ty = tid >> 4;
    const int row0 = blockIdx.x * 128, col0 = blockIdx.y * 128;
    // staging indices
    const int arow = tid >> 2;          // 0..63 (and +64)
    const int acq = tid & 3;            // k-chunk of 4
    const int bc = tid & 31;            // col block of 4
    const int bk = tid >> 5;            // 0..7 (and +8)
    float acc[8][8] = {};

    for (int k0 = 0; k0 < K; k0 += 16) {
        // stage A (two rows per thread), transposed into As[k][row]
#pragma unroll
        for (int h = 0; h < 2; ++h) {
            int r = arow + 64 * h;
            float4 a = (row0 + r < M)
                ? *(const float4*)&A[(size_t)(row0 + r) * K + k0 + acq * 4]
                : make_float4(0.f, 0.f, 0.f, 0.f);
            As[acq * 4 + 0][r] = a.x;
            As[acq * 4 + 1][r] = a.y;
            As[acq * 4 + 2][r] = a.z;
            As[acq * 4 + 3][r] = a.w;
        }
        // stage B (two k-rows per thread), swizzled blocks
#pragma unroll
        for (int h = 0; h < 2; ++h) {
            int kk = bk + 8 * h;
            float4 b = *(const float4*)&B[(size_t)(k0 + kk) * HC + col0 + bc * 4];
            *(float4*)&Bs[kk * 128 + 4 * bswz(bc)] = b;
        }
        __syncthreads();
#pragma unroll
        for (int kk = 0; kk < 16; ++kk) {
            float4 a0 = *(const float4*)&As[kk][ty * 4];
            float4 a1 = *(const float4*)&As[kk][64 + ty * 4];
            float4 b0 = *(const float4*)&Bs[kk * 128 + 4 * bswz(tx)];
            float4 b1 = *(const float4*)&Bs[kk * 128 + 4 * bswz(tx + 16)];
            float av[8] = {a0.x, a0.y, a0.z, a0.w, a1.x, a1.y, a1.z, a1.w};
            float bv[8] = {b0.x, b0.y, b0.z, b0.w, b1.x, b1.y, b1.z, b1.w};
#pragma unroll
            for (int i = 0; i < 8; ++i)
#pragma unroll
                for (int j = 0; j < 8; ++j) acc[i][j] = fmaf(av[i], bv[j], acc[i][j]);
        }
        __syncthreads();
    }
#pragma unroll
    for (int i = 0; i < 8; ++i) {
        int r = row0 + (i < 4 ? ty * 4 + i : 64 + ty * 4 + (i - 4));
        if (r < M) {
            float4 o0 = make_float4(acc[i][0], acc[i][1], acc[i][2], acc[i][3]);
            float4 o1 = make_float4(acc[i][4], acc[i][5], acc[i][6], acc[i][7]);
            *(float4*)&C[(size_t)r * HC + col0 + tx * 4] = o0;
            *(float4*)&C[(size_t)r * HC + col0 + 64 + tx * 4] = o1;
        }
    }
}

// ------------------------------------------------------------------
// per-node attention logits
__global__ void alpha_kernel(const float* __restrict__ h, const float* __restrict__ a_src,
                             const float* __restrict__ a_dst, float* __restrict__ asrc,
                             float* __restrict__ adst, int n) {
    int t = blockIdx.x * blockDim.x + threadIdx.x;
    if (t >= n * HEADS) return;
    int node = t >> 3, head = t & 7;
    const float4* hp = (const float4*)(h + (size_t)node * HC + head * HID);
    const float4* w1 = (const float4*)(a_src + head * HID);
    const float4* w2 = (const float4*)(a_dst + head * HID);
    float s1 = 0.f, s2 = 0.f;
#pragma unroll
    for (int q = 0; q < 8; ++q) {
        float4 hv = hp[q], a1 = w1[q], a2 = w2[q];
        s1 += hv.x * a1.x + hv.y * a1.y + hv.z * a1.z + hv.w * a1.w;
        s2 += hv.x * a2.x + hv.y * a2.y + hv.z * a2.z + hv.w * a2.w;
    }
    asrc[t] = s1;
    adst[t] = s2;
}

// ------------------------------------------------------------------
// one wave per dst node: online-softmax over in-edges (+self-loop), 4 ch/lane.
// LAST: fuse the mean-pool dot product with lin_w (skip writing h entirely).
template <bool LAST>
__global__ __launch_bounds__(256) void gat_aggregate(
    const float* __restrict__ h, const float* __restrict__ asrc,
    const float* __restrict__ adst, const int* __restrict__ row_ptr,
    const int* __restrict__ srcs, const float* __restrict__ bias,
    float* __restrict__ out, const void* __restrict__ batch,
    const int* __restrict__ mode, const float* __restrict__ lin_w,
    float* __restrict__ gsum, float* __restrict__ gcnt, int n) {
    int node = (blockIdx.x * blockDim.x + threadIdx.x) >> 6;
    int lane = threadIdx.x & 63;
    if (node >= n) return;
    int head = lane >> 3;   // 4 channels/lane stay within one head
    int c0 = lane * 4;
    float ad = adst[node * HEADS + head];
    float e0 = asrc[node * HEADS + head] + ad;
    e0 = e0 > 0.f ? e0 : NEG_SLOPE * e0;
    float m = e0, denom = 1.f;
    float4 acc = *(const float4*)(h + (size_t)node * HC + c0);   // self-loop
    int beg = row_ptr[node], end = row_ptr[node + 1];
    for (int j = beg; j < end; ++j) {
        int s = srcs[j];
        float as = asrc[s * HEADS + head];
        float ee = as + ad;
        ee = ee > 0.f ? ee : NEG_SLOPE * ee;
        float nm = fmaxf(m, ee);
        float sc = __expf(m - nm);
        float p = __expf(ee - nm);
        float4 hv = *(const float4*)(h + (size_t)s * HC + c0);
        denom = denom * sc + p;
        acc.x = fmaf(acc.x, sc, p * hv.x);
        acc.y = fmaf(acc.y, sc, p * hv.y);
        acc.z = fmaf(acc.z, sc, p * hv.z);
        acc.w = fmaf(acc.w, sc, p * hv.w);
        m = nm;
    }
    float inv = 1.f / (denom + 1e-16f);
    float4 b = *(const float4*)(bias + c0);
    float o[4] = {fmaf(acc.x, inv, b.x), fmaf(acc.y, inv, b.y),
                  fmaf(acc.z, inv, b.z), fmaf(acc.w, inv, b.w)};
#pragma unroll
    for (int q = 0; q < 4; ++q) o[q] = o[q] > 0.f ? o[q] : __expf(o[q]) - 1.f;  // ELU
    if (!LAST) {
        *(float4*)(out + (size_t)node * HC + c0) = make_float4(o[0], o[1], o[2], o[3]);
    } else {
        float4 w = *(const float4*)(lin_w + c0);
        float s = o[0] * w.x + o[1] * w.y + o[2] * w.z + o[3] * w.w;
#pragma unroll
        for (int off = 32; off > 0; off >>= 1) s += __shfl_down(s, off, 64);
        if (lane == 0) {
            int g = IDX(batch, node, mode[0]);
            atomicAdd(&gsum[g], s);
            atomicAdd(&gcnt[g], 1.f);
        }
    }
}

__global__ void final_kernel(const float* __restrict__ gsum, const float* __restrict__ gcnt,
                             const float* __restrict__ lin_b, float* __restrict__ outp) {
    int g = blockIdx.x * blockDim.x + threadIdx.x;
    if (g >= GRAPHS) return;
    float c = gcnt[g];
    c = c > 1.f ? c : 1.f;
    outp[g] = gsum[g] / c + lin_b[0];
}

// ------------------------------------------------------------------
extern "C" void kernel_launch(void* const* d_in, const int* in_sizes, int n_in,
                              void* d_out, int out_size, void* d_ws, size_t ws_size,
                              hipStream_t stream) {
    const float* x = (const float*)d_in[0];
    const void* edge = d_in[1];
    const void* batch = d_in[2];
    const float* W[3]    = {(const float*)d_in[3], (const float*)d_in[7],  (const float*)d_in[11]};
    const float* ASRC[3] = {(const float*)d_in[4], (const float*)d_in[8],  (const float*)d_in[12]};
    const float* ADST[3] = {(const float*)d_in[5], (const float*)d_in[9],  (const float*)d_in[13]};
    const float* BIAS[3] = {(const float*)d_in[6], (const float*)d_in[10], (const float*)d_in[14]};
    const float* lin_w = (const float*)d_in[15];
    const float* lin_b = (const float*)d_in[16];
    float* outp = (float*)d_out;

    const int n = in_sizes[0] / 128;  // 50000
    const int e = in_sizes[1] / 2;    // 800000
    const int IN_CH = 128;

    char* ws = (char*)d_ws;
    size_t off = 0;
    auto alloc = [&](size_t bytes) -> void* {
        void* p = ws + off;
        off = (off + bytes + 255) & ~(size_t)255;
        return p;
    };
    float* hbuf   = (float*)alloc((size_t)n * HC * 4);
    float* gbuf   = (float*)alloc((size_t)n * HC * 4);
    float* as_buf = (float*)alloc((size_t)n * HEADS * 4);
    float* ad_buf = (float*)alloc((size_t)n * HEADS * 4);
    int* hist     = (int*)alloc((size_t)n * 4);          // reused as fill
    int* row_ptr  = (int*)alloc((size_t)(n + 1) * 4);
    int* bsum     = (int*)alloc(1024);
    int* mode     = (int*)alloc(256);
    int* srcs     = (int*)alloc((size_t)e * 4);
    float* gsum   = (float*)alloc((size_t)GRAPHS * 4);
    float* gcnt   = (float*)alloc((size_t)GRAPHS * 4);
    if (off > ws_size) return;

    const int nb = (n + 255) / 256;

    detect_kernel<<<1, 256, 0, stream>>>((const unsigned int*)edge, mode, e);

    // CSR build
    hipMemsetAsync(hist, 0, (size_t)n * 4, stream);
    hist_kernel<<<(e + 255) / 256, 256, 0, stream>>>(edge, mode, hist, e);
    scan1<<<nb, 256, 0, stream>>>(hist, row_ptr, bsum, n);
    scan2<<<1, 256, 0, stream>>>(bsum, nb);
    scan3<<<nb, 256, 0, stream>>>(row_ptr, bsum, n, e);
    hipMemsetAsync(hist, 0, (size_t)n * 4, stream);
    scatter_kernel<<<(e + 255) / 256, 256, 0, stream>>>(edge, mode, row_ptr, hist, srcs, e);

    hipMemsetAsync(gsum, 0, (size_t)GRAPHS * 4, stream);
    hipMemsetAsync(gcnt, 0, (size_t)GRAPHS * 4, stream);

    dim3 gemm_grid((n + 127) / 128, 2);
    const float* cur_in = x;
    int K = IN_CH;
    for (int l = 0; l < 3; ++l) {
        gemm128<<<gemm_grid, 256, 0, stream>>>(cur_in, W[l], hbuf, n, K);
        alpha_kernel<<<(n * HEADS + 255) / 256, 256, 0, stream>>>(hbuf, ASRC[l], ADST[l],
                                                                  as_buf, ad_buf, n);
        if (l < 2) {
            gat_aggregate<false><<<(n + 3) / 4, 256, 0, stream>>>(
                hbuf, as_buf, ad_buf, row_ptr, srcs, BIAS[l], gbuf,
                batch, mode, lin_w, gsum, gcnt, n);
        } else {
            gat_aggregate<true><<<(n + 3) / 4, 256, 0, stream>>>(
                hbuf, as_buf, ad_buf, row_ptr, srcs, BIAS[l], nullptr,
                batch, mode, lin_w, gsum, gcnt, n);
        }
        cur_in = gbuf;
        K = HC;
    }

    final_kernel<<<2, 256, 0, stream>>>(gsum, gcnt, lin_b, outp);
}

// Round 3
// 840.937 us; speedup vs baseline: 1.3752x; 1.0839x over previous
//
#include <hip/hip_runtime.h>

#define HC 256      // HEADS*HID
#define HEADS 8
#define HID 32
#define GRAPHS 512
#define NEG_SLOPE 0.2f

// ------------------------------------------------------------------
// int32/int64 index handling (JAX may emit either for edge_index/batch)
__device__ __forceinline__ int IDX(const void* p, long long i, int mode) {
    if (mode) return (int)((const long long*)p)[i];
    return ((const int*)p)[i];
}

__global__ void detect_kernel(const unsigned int* __restrict__ words, int* __restrict__ mode, int e) {
    __shared__ unsigned int red[256];
    unsigned int v = 0;
    int lim = e < 4096 ? e : 4096;
    for (int i = threadIdx.x; i < lim; i += 256) v |= words[2 * i + 1];
    red[threadIdx.x] = v;
    __syncthreads();
    for (int off = 128; off > 0; off >>= 1) {
        if (threadIdx.x < off) red[threadIdx.x] |= red[threadIdx.x + off];
        __syncthreads();
    }
    if (threadIdx.x == 0) *mode = (red[0] == 0u) ? 1 : 0;  // 1 => int64
}

// ------------------------------------------------------------------
// CSR build: histogram -> scan -> scatter
__global__ void hist_kernel(const void* __restrict__ edge, const int* __restrict__ mode,
                            int* __restrict__ hist, int e) {
    int m = mode[0];
    int i = blockIdx.x * blockDim.x + threadIdx.x;
    if (i < e) atomicAdd(&hist[IDX(edge, (long long)e + i, m)], 1);
}

__global__ void scan1(const int* __restrict__ hist, int* __restrict__ excl,
                      int* __restrict__ bsum, int n) {
    __shared__ int buf[256];
    int i = blockIdx.x * 256 + threadIdx.x;
    int v = (i < n) ? hist[i] : 0;
    buf[threadIdx.x] = v;
    __syncthreads();
    for (int off = 1; off < 256; off <<= 1) {
        int t = (threadIdx.x >= (unsigned)off) ? buf[threadIdx.x - off] : 0;
        __syncthreads();
        buf[threadIdx.x] += t;
        __syncthreads();
    }
    if (i < n) excl[i] = buf[threadIdx.x] - v;
    if (threadIdx.x == 255) bsum[blockIdx.x] = buf[255];
}

__global__ void scan2(int* __restrict__ bsum, int nb) {
    __shared__ int buf[256];
    int v = (threadIdx.x < (unsigned)nb) ? bsum[threadIdx.x] : 0;
    buf[threadIdx.x] = v;
    __syncthreads();
    for (int off = 1; off < 256; off <<= 1) {
        int t = (threadIdx.x >= (unsigned)off) ? buf[threadIdx.x - off] : 0;
        __syncthreads();
        buf[threadIdx.x] += t;
        __syncthreads();
    }
    if (threadIdx.x < (unsigned)nb) bsum[threadIdx.x] = buf[threadIdx.x] - v;  // exclusive
}

__global__ void scan3(int* __restrict__ row_ptr, const int* __restrict__ bsum, int n, int e) {
    int i = blockIdx.x * 256 + threadIdx.x;
    if (i < n) row_ptr[i] += bsum[i >> 8];
    if (i == 0) row_ptr[n] = e;
}

__global__ void scatter_kernel(const void* __restrict__ edge, const int* __restrict__ mode,
                               const int* __restrict__ row_ptr, int* __restrict__ fill,
                               int* __restrict__ out, int e) {
    int m = mode[0];
    int i = blockIdx.x * blockDim.x + threadIdx.x;
    if (i < e) {
        int d = IDX(edge, (long long)e + i, m);
        int pos = row_ptr[d] + atomicAdd(&fill[d], 1);
        out[pos] = IDX(edge, (long long)i, m);
    }
}

// ------------------------------------------------------------------
// fp32 GEMM: C[M,256] = A[M,K] @ B[K,256], tile 128x128, 8x8 micro (4+4 split)
__device__ __forceinline__ int bswz(int b) { return b ^ ((b >> 3) & 3); }  // involution

__global__ __launch_bounds__(256) void gemm128(const float* __restrict__ A,
                                               const float* __restrict__ B,
                                               float* __restrict__ C, int M, int K) {
    __shared__ float As[16][132];       // +4 pad: transpose-write 2-way max
    __shared__ float Bs[16 * 128];      // XOR-swizzled blocks of 4 floats
    const int tid = threadIdx.x;
    const int tx = tid & 15, ty = tid >> 4;
    const int row0 = blockIdx.x * 128, col0 = blockIdx.y * 128;
    const int arow = tid >> 2;
    const int acq = tid & 3;
    const int bc = tid & 31;
    const int bk = tid >> 5;
    float acc[8][8] = {};

    for (int k0 = 0; k0 < K; k0 += 16) {
#pragma unroll
        for (int h = 0; h < 2; ++h) {
            int r = arow + 64 * h;
            float4 a = (row0 + r < M)
                ? *(const float4*)&A[(size_t)(row0 + r) * K + k0 + acq * 4]
                : make_float4(0.f, 0.f, 0.f, 0.f);
            As[acq * 4 + 0][r] = a.x;
            As[acq * 4 + 1][r] = a.y;
            As[acq * 4 + 2][r] = a.z;
            As[acq * 4 + 3][r] = a.w;
        }
#pragma unroll
        for (int h = 0; h < 2; ++h) {
            int kk = bk + 8 * h;
            float4 b = *(const float4*)&B[(size_t)(k0 + kk) * HC + col0 + bc * 4];
            *(float4*)&Bs[kk * 128 + 4 * bswz(bc)] = b;
        }
        __syncthreads();
#pragma unroll
        for (int kk = 0; kk < 16; ++kk) {
            float4 a0 = *(const float4*)&As[kk][ty * 4];
            float4 a1 = *(const float4*)&As[kk][64 + ty * 4];
            float4 b0 = *(const float4*)&Bs[kk * 128 + 4 * bswz(tx)];
            float4 b1 = *(const float4*)&Bs[kk * 128 + 4 * bswz(tx + 16)];
            float av[8] = {a0.x, a0.y, a0.z, a0.w, a1.x, a1.y, a1.z, a1.w};
            float bv[8] = {b0.x, b0.y, b0.z, b0.w, b1.x, b1.y, b1.z, b1.w};
#pragma unroll
            for (int i = 0; i < 8; ++i)
#pragma unroll
                for (int j = 0; j < 8; ++j) acc[i][j] = fmaf(av[i], bv[j], acc[i][j]);
        }
        __syncthreads();
    }
#pragma unroll
    for (int i = 0; i < 8; ++i) {
        int r = row0 + (i < 4 ? ty * 4 + i : 64 + ty * 4 + (i - 4));
        if (r < M) {
            float4 o0 = make_float4(acc[i][0], acc[i][1], acc[i][2], acc[i][3]);
            float4 o1 = make_float4(acc[i][4], acc[i][5], acc[i][6], acc[i][7]);
            *(float4*)&C[(size_t)r * HC + col0 + tx * 4] = o0;
            *(float4*)&C[(size_t)r * HC + col0 + 64 + tx * 4] = o1;
        }
    }
}

// ------------------------------------------------------------------
// per-node attention logits, layout [N, H]
__global__ void alpha_kernel(const float* __restrict__ h, const float* __restrict__ a_src,
                             const float* __restrict__ a_dst, float* __restrict__ asrc,
                             float* __restrict__ adst, int n) {
    int t = blockIdx.x * blockDim.x + threadIdx.x;
    if (t >= n * HEADS) return;
    int node = t >> 3, head = t & 7;
    const float4* hp = (const float4*)(h + (size_t)node * HC + head * HID);
    const float4* w1 = (const float4*)(a_src + head * HID);
    const float4* w2 = (const float4*)(a_dst + head * HID);
    float s1 = 0.f, s2 = 0.f;
#pragma unroll
    for (int q = 0; q < 8; ++q) {
        float4 hv = hp[q], a1 = w1[q], a2 = w2[q];
        s1 += hv.x * a1.x + hv.y * a1.y + hv.z * a1.z + hv.w * a1.w;
        s2 += hv.x * a2.x + hv.y * a2.y + hv.z * a2.z + hv.w * a2.w;
    }
    asrc[t] = s1;
    adst[t] = s2;
}

// ------------------------------------------------------------------
// one wave per dst node, two-pass softmax:
//  pass 1: lanes = (edge-group 0..7) x (head 0..7), online max/denom, shfl reduce
//  pass 2: channel-parallel weighted gather, x4 unrolled (4 rows in flight)
// LAST: fuse mean-pool dot with lin_w (skip writing h).
template <bool LAST>
__global__ __launch_bounds__(256) void gat_aggregate(
    const float* __restrict__ h, const float* __restrict__ asrc,
    const float* __restrict__ adst, const int* __restrict__ row_ptr,
    const int* __restrict__ srcs, const float* __restrict__ bias,
    float* __restrict__ out, const void* __restrict__ batch,
    const int* __restrict__ mode, const float* __restrict__ lin_w,
    float* __restrict__ gsum, float* __restrict__ gcnt, int n) {
    int node = (int)((blockIdx.x * blockDim.x + threadIdx.x) >> 6);
    node = __builtin_amdgcn_readfirstlane(node);   // wave-uniform -> SGPR
    if (node >= n) return;
    const int lane = threadIdx.x & 63;
    const int h1 = lane & 7;       // pass-1 head
    const int eg = lane >> 3;      // pass-1 edge group / pass-2 head
    const int head = eg;
    const int c0 = lane * 4;
    const int beg = row_ptr[node], end = row_ptr[node + 1];

    // ---------------- pass 1: per-head max & denom over in-edges
    float ad1 = adst[node * 8 + h1];
    float m = -1e30f, d = 0.f;
    for (int j = beg + eg; j < end; j += 8) {
        int s = srcs[j];
        float e = asrc[s * 8 + h1] + ad1;
        e = e > 0.f ? e : NEG_SLOPE * e;
        float nm = fmaxf(m, e);
        d = d * __expf(m - nm) + __expf(e - nm);
        m = nm;
    }
#pragma unroll
    for (int off = 8; off < 64; off <<= 1) {
        float mo = __shfl_xor(m, off, 64);
        float dd = __shfl_xor(d, off, 64);
        float nm = fmaxf(m, mo);
        d = d * __expf(m - nm) + dd * __expf(mo - nm);
        m = nm;
    }
    // lane l needs head l>>3; that head's reduced value lives in lane (l>>3)
    float mh = __shfl(m, head, 64);
    float dh = __shfl(d, head, 64);
    // fold in self-loop
    float adh = adst[node * 8 + head];
    float e0 = asrc[node * 8 + head] + adh;
    e0 = e0 > 0.f ? e0 : NEG_SLOPE * e0;
    float nm2 = fmaxf(mh, e0);
    dh = dh * __expf(mh - nm2) + __expf(e0 - nm2);
    mh = nm2;
    float invd = 1.f / (dh + 1e-16f);

    // ---------------- pass 2: weighted gather, 4 rows in flight
    float w0 = __expf(e0 - mh) * invd;
    float4 hv0 = *(const float4*)(h + (size_t)node * HC + c0);
    float4 acc = make_float4(w0 * hv0.x, w0 * hv0.y, w0 * hv0.z, w0 * hv0.w);
    int j = beg;
    for (; j + 4 <= end; j += 4) {
        int s0 = srcs[j], s1 = srcs[j + 1], s2 = srcs[j + 2], s3 = srcs[j + 3];
        float4 g0 = *(const float4*)(h + (size_t)s0 * HC + c0);
        float4 g1 = *(const float4*)(h + (size_t)s1 * HC + c0);
        float4 g2 = *(const float4*)(h + (size_t)s2 * HC + c0);
        float4 g3 = *(const float4*)(h + (size_t)s3 * HC + c0);
        float a0 = asrc[s0 * 8 + head], a1 = asrc[s1 * 8 + head];
        float a2 = asrc[s2 * 8 + head], a3 = asrc[s3 * 8 + head];
        float e;
        e = a0 + adh; e = e > 0.f ? e : NEG_SLOPE * e; float x0 = __expf(e - mh) * invd;
        e = a1 + adh; e = e > 0.f ? e : NEG_SLOPE * e; float x1 = __expf(e - mh) * invd;
        e = a2 + adh; e = e > 0.f ? e : NEG_SLOPE * e; float x2 = __expf(e - mh) * invd;
        e = a3 + adh; e = e > 0.f ? e : NEG_SLOPE * e; float x3 = __expf(e - mh) * invd;
        acc.x += x0 * g0.x + x1 * g1.x + x2 * g2.x + x3 * g3.x;
        acc.y += x0 * g0.y + x1 * g1.y + x2 * g2.y + x3 * g3.y;
        acc.z += x0 * g0.z + x1 * g1.z + x2 * g2.z + x3 * g3.z;
        acc.w += x0 * g0.w + x1 * g1.w + x2 * g2.w + x3 * g3.w;
    }
    for (; j < end; ++j) {
        int s = srcs[j];
        float4 g = *(const float4*)(h + (size_t)s * HC + c0);
        float e = asrc[s * 8 + head] + adh;
        e = e > 0.f ? e : NEG_SLOPE * e;
        float w = __expf(e - mh) * invd;
        acc.x += w * g.x; acc.y += w * g.y; acc.z += w * g.z; acc.w += w * g.w;
    }

    float4 b = *(const float4*)(bias + c0);
    float o[4] = {acc.x + b.x, acc.y + b.y, acc.z + b.z, acc.w + b.w};
#pragma unroll
    for (int q = 0; q < 4; ++q) o[q] = o[q] > 0.f ? o[q] : __expf(o[q]) - 1.f;  // ELU
    if (!LAST) {
        *(float4*)(out + (size_t)node * HC + c0) = make_float4(o[0], o[1], o[2], o[3]);
    } else {
        float4 w = *(const float4*)(lin_w + c0);
        float s = o[0] * w.x + o[1] * w.y + o[2] * w.z + o[3] * w.w;
#pragma unroll
        for (int off = 32; off > 0; off >>= 1) s += __shfl_down(s, off, 64);
        if (lane == 0) {
            int g = IDX(batch, node, mode[0]);
            atomicAdd(&gsum[g], s);
            atomicAdd(&gcnt[g], 1.f);
        }
    }
}

__global__ void final_kernel(const float* __restrict__ gsum, const float* __restrict__ gcnt,
                             const float* __restrict__ lin_b, float* __restrict__ outp) {
    int g = blockIdx.x * blockDim.x + threadIdx.x;
    if (g >= GRAPHS) return;
    float c = gcnt[g];
    c = c > 1.f ? c : 1.f;
    outp[g] = gsum[g] / c + lin_b[0];
}

// ------------------------------------------------------------------
extern "C" void kernel_launch(void* const* d_in, const int* in_sizes, int n_in,
                              void* d_out, int out_size, void* d_ws, size_t ws_size,
                              hipStream_t stream) {
    const float* x = (const float*)d_in[0];
    const void* edge = d_in[1];
    const void* batch = d_in[2];
    const float* W[3]    = {(const float*)d_in[3], (const float*)d_in[7],  (const float*)d_in[11]};
    const float* ASRC[3] = {(const float*)d_in[4], (const float*)d_in[8],  (const float*)d_in[12]};
    const float* ADST[3] = {(const float*)d_in[5], (const float*)d_in[9],  (const float*)d_in[13]};
    const float* BIAS[3] = {(const float*)d_in[6], (const float*)d_in[10], (const float*)d_in[14]};
    const float* lin_w = (const float*)d_in[15];
    const float* lin_b = (const float*)d_in[16];
    float* outp = (float*)d_out;

    const int n = in_sizes[0] / 128;  // 50000
    const int e = in_sizes[1] / 2;    // 800000
    const int IN_CH = 128;

    char* ws = (char*)d_ws;
    size_t off = 0;
    auto alloc = [&](size_t bytes) -> void* {
        void* p = ws + off;
        off = (off + bytes + 255) & ~(size_t)255;
        return p;
    };
    float* hbuf   = (float*)alloc((size_t)n * HC * 4);
    float* gbuf   = (float*)alloc((size_t)n * HC * 4);
    float* as_buf = (float*)alloc((size_t)n * HEADS * 4);
    float* ad_buf = (float*)alloc((size_t)n * HEADS * 4);
    int* hist     = (int*)alloc((size_t)n * 4);          // reused as fill
    int* row_ptr  = (int*)alloc((size_t)(n + 1) * 4);
    int* bsum     = (int*)alloc(1024);
    int* mode     = (int*)alloc(256);
    int* srcs     = (int*)alloc((size_t)e * 4);
    float* gsum   = (float*)alloc((size_t)GRAPHS * 4);
    float* gcnt   = (float*)alloc((size_t)GRAPHS * 4);
    if (off > ws_size) return;

    const int nb = (n + 255) / 256;

    detect_kernel<<<1, 256, 0, stream>>>((const unsigned int*)edge, mode, e);

    // CSR build
    hipMemsetAsync(hist, 0, (size_t)n * 4, stream);
    hist_kernel<<<(e + 255) / 256, 256, 0, stream>>>(edge, mode, hist, e);
    scan1<<<nb, 256, 0, stream>>>(hist, row_ptr, bsum, n);
    scan2<<<1, 256, 0, stream>>>(bsum, nb);
    scan3<<<nb, 256, 0, stream>>>(row_ptr, bsum, n, e);
    hipMemsetAsync(hist, 0, (size_t)n * 4, stream);
    scatter_kernel<<<(e + 255) / 256, 256, 0, stream>>>(edge, mode, row_ptr, hist, srcs, e);

    hipMemsetAsync(gsum, 0, (size_t)GRAPHS * 4, stream);
    hipMemsetAsync(gcnt, 0, (size_t)GRAPHS * 4, stream);

    dim3 gemm_grid((n + 127) / 128, 2);
    const float* cur_in = x;
    int K = IN_CH;
    for (int l = 0; l < 3; ++l) {
        gemm128<<<gemm_grid, 256, 0, stream>>>(cur_in, W[l], hbuf, n, K);
        alpha_kernel<<<(n * HEADS + 255) / 256, 256, 0, stream>>>(hbuf, ASRC[l], ADST[l],
                                                                  as_buf, ad_buf, n);
        if (l < 2) {
            gat_aggregate<false><<<(n + 3) / 4, 256, 0, stream>>>(
                hbuf, as_buf, ad_buf, row_ptr, srcs, BIAS[l], gbuf,
                batch, mode, lin_w, gsum, gcnt, n);
        } else {
            gat_aggregate<true><<<(n + 3) / 4, 256, 0, stream>>>(
                hbuf, as_buf, ad_buf, row_ptr, srcs, BIAS[l], nullptr,
                batch, mode, lin_w, gsum, gcnt, n);
        }
        cur_in = gbuf;
        K = HC;
    }

    final_kernel<<<2, 256, 0, stream>>>(gsum, gcnt, lin_b, outp);
}

// Round 4
// 703.605 us; speedup vs baseline: 1.6436x; 1.1952x over previous
//
#include <hip/hip_runtime.h>

#define HC 256      // HEADS*HID
#define HEADS 8
#define HID 32
#define GRAPHS 512
#define NEG_SLOPE 0.2f

// ------------------------------------------------------------------
// bf16 helpers (round-to-nearest-even)
__device__ __forceinline__ unsigned short f2bf(float x) {
    unsigned u = __float_as_uint(x);
    return (unsigned short)((u + 0x7fffu + ((u >> 16) & 1u)) >> 16);
}
__device__ __forceinline__ float bf2f(unsigned short b) {
    return __uint_as_float(((unsigned)b) << 16);
}

// int32/int64 index handling (JAX may emit either for edge_index/batch)
__device__ __forceinline__ int IDX(const void* p, long long i, int mode) {
    if (mode) return (int)((const long long*)p)[i];
    return ((const int*)p)[i];
}

__global__ void detect_kernel(const unsigned int* __restrict__ words, int* __restrict__ mode, int e) {
    __shared__ unsigned int red[256];
    unsigned int v = 0;
    int lim = e < 4096 ? e : 4096;
    for (int i = threadIdx.x; i < lim; i += 256) v |= words[2 * i + 1];
    red[threadIdx.x] = v;
    __syncthreads();
    for (int off = 128; off > 0; off >>= 1) {
        if (threadIdx.x < off) red[threadIdx.x] |= red[threadIdx.x + off];
        __syncthreads();
    }
    if (threadIdx.x == 0) *mode = (red[0] == 0u) ? 1 : 0;  // 1 => int64
}

// ------------------------------------------------------------------
// CSR build: histogram -> scan -> scatter
__global__ void hist_kernel(const void* __restrict__ edge, const int* __restrict__ mode,
                            int* __restrict__ hist, int e) {
    int m = mode[0];
    int i = blockIdx.x * blockDim.x + threadIdx.x;
    if (i < e) atomicAdd(&hist[IDX(edge, (long long)e + i, m)], 1);
}

__global__ void scan1(const int* __restrict__ hist, int* __restrict__ excl,
                      int* __restrict__ bsum, int n) {
    __shared__ int buf[256];
    int i = blockIdx.x * 256 + threadIdx.x;
    int v = (i < n) ? hist[i] : 0;
    buf[threadIdx.x] = v;
    __syncthreads();
    for (int off = 1; off < 256; off <<= 1) {
        int t = (threadIdx.x >= (unsigned)off) ? buf[threadIdx.x - off] : 0;
        __syncthreads();
        buf[threadIdx.x] += t;
        __syncthreads();
    }
    if (i < n) excl[i] = buf[threadIdx.x] - v;
    if (threadIdx.x == 255) bsum[blockIdx.x] = buf[255];
}

__global__ void scan2(int* __restrict__ bsum, int nb) {
    __shared__ int buf[256];
    int v = (threadIdx.x < (unsigned)nb) ? bsum[threadIdx.x] : 0;
    buf[threadIdx.x] = v;
    __syncthreads();
    for (int off = 1; off < 256; off <<= 1) {
        int t = (threadIdx.x >= (unsigned)off) ? buf[threadIdx.x - off] : 0;
        __syncthreads();
        buf[threadIdx.x] += t;
        __syncthreads();
    }
    if (threadIdx.x < (unsigned)nb) bsum[threadIdx.x] = buf[threadIdx.x] - v;  // exclusive
}

__global__ void scan3(int* __restrict__ row_ptr, const int* __restrict__ bsum, int n, int e) {
    int i = blockIdx.x * 256 + threadIdx.x;
    if (i < n) row_ptr[i] += bsum[i >> 8];
    if (i == 0) row_ptr[n] = e;
}

__global__ void scatter_kernel(const void* __restrict__ edge, const int* __restrict__ mode,
                               const int* __restrict__ row_ptr, int* __restrict__ fill,
                               int* __restrict__ outs, int* __restrict__ outd, int e) {
    int m = mode[0];
    int i = blockIdx.x * blockDim.x + threadIdx.x;
    if (i < e) {
        int d = IDX(edge, (long long)e + i, m);
        int pos = row_ptr[d] + atomicAdd(&fill[d], 1);
        outs[pos] = IDX(edge, (long long)i, m);
        outd[pos] = d;
    }
}

// ------------------------------------------------------------------
// fp32 GEMM: C[M,256] = A[M,K] @ B[K,256], tile 128x128, 8x8 micro (4+4 split)
// Also emits a bf16 copy of C for the gather table.
__device__ __forceinline__ int bswz(int b) { return b ^ ((b >> 3) & 3); }  // involution

__global__ __launch_bounds__(256) void gemm128(const float* __restrict__ A,
                                               const float* __restrict__ B,
                                               float* __restrict__ C,
                                               unsigned short* __restrict__ C16,
                                               int M, int K) {
    __shared__ float As[16][132];
    __shared__ float Bs[16 * 128];
    const int tid = threadIdx.x;
    const int tx = tid & 15, ty = tid >> 4;
    const int row0 = blockIdx.x * 128, col0 = blockIdx.y * 128;
    const int arow = tid >> 2;
    const int acq = tid & 3;
    const int bc = tid & 31;
    const int bk = tid >> 5;
    float acc[8][8] = {};

    for (int k0 = 0; k0 < K; k0 += 16) {
#pragma unroll
        for (int h = 0; h < 2; ++h) {
            int r = arow + 64 * h;
            float4 a = (row0 + r < M)
                ? *(const float4*)&A[(size_t)(row0 + r) * K + k0 + acq * 4]
                : make_float4(0.f, 0.f, 0.f, 0.f);
            As[acq * 4 + 0][r] = a.x;
            As[acq * 4 + 1][r] = a.y;
            As[acq * 4 + 2][r] = a.z;
            As[acq * 4 + 3][r] = a.w;
        }
#pragma unroll
        for (int h = 0; h < 2; ++h) {
            int kk = bk + 8 * h;
            float4 b = *(const float4*)&B[(size_t)(k0 + kk) * HC + col0 + bc * 4];
            *(float4*)&Bs[kk * 128 + 4 * bswz(bc)] = b;
        }
        __syncthreads();
#pragma unroll
        for (int kk = 0; kk < 16; ++kk) {
            float4 a0 = *(const float4*)&As[kk][ty * 4];
            float4 a1 = *(const float4*)&As[kk][64 + ty * 4];
            float4 b0 = *(const float4*)&Bs[kk * 128 + 4 * bswz(tx)];
            float4 b1 = *(const float4*)&Bs[kk * 128 + 4 * bswz(tx + 16)];
            float av[8] = {a0.x, a0.y, a0.z, a0.w, a1.x, a1.y, a1.z, a1.w};
            float bv[8] = {b0.x, b0.y, b0.z, b0.w, b1.x, b1.y, b1.z, b1.w};
#pragma unroll
            for (int i = 0; i < 8; ++i)
#pragma unroll
                for (int j = 0; j < 8; ++j) acc[i][j] = fmaf(av[i], bv[j], acc[i][j]);
        }
        __syncthreads();
    }
#pragma unroll
    for (int i = 0; i < 8; ++i) {
        int r = row0 + (i < 4 ? ty * 4 + i : 64 + ty * 4 + (i - 4));
        if (r < M) {
            float4 o0 = make_float4(acc[i][0], acc[i][1], acc[i][2], acc[i][3]);
            float4 o1 = make_float4(acc[i][4], acc[i][5], acc[i][6], acc[i][7]);
            *(float4*)&C[(size_t)r * HC + col0 + tx * 4] = o0;
            *(float4*)&C[(size_t)r * HC + col0 + 64 + tx * 4] = o1;
            ushort4 u0 = {f2bf(o0.x), f2bf(o0.y), f2bf(o0.z), f2bf(o0.w)};
            ushort4 u1 = {f2bf(o1.x), f2bf(o1.y), f2bf(o1.z), f2bf(o1.w)};
            *(ushort4*)&C16[(size_t)r * HC + col0 + tx * 4] = u0;
            *(ushort4*)&C16[(size_t)r * HC + col0 + 64 + tx * 4] = u1;
        }
    }
}

// ------------------------------------------------------------------
// per-node attention logits, layout [N, H]
__global__ void alpha_kernel(const float* __restrict__ h, const float* __restrict__ a_src,
                             const float* __restrict__ a_dst, float* __restrict__ asrc,
                             float* __restrict__ adst, int n) {
    int t = blockIdx.x * blockDim.x + threadIdx.x;
    if (t >= n * HEADS) return;
    int node = t >> 3, head = t & 7;
    const float4* hp = (const float4*)(h + (size_t)node * HC + head * HID);
    const float4* w1 = (const float4*)(a_src + head * HID);
    const float4* w2 = (const float4*)(a_dst + head * HID);
    float s1 = 0.f, s2 = 0.f;
#pragma unroll
    for (int q = 0; q < 8; ++q) {
        float4 hv = hp[q], a1 = w1[q], a2 = w2[q];
        s1 += hv.x * a1.x + hv.y * a1.y + hv.z * a1.z + hv.w * a1.w;
        s2 += hv.x * a2.x + hv.y * a2.y + hv.z * a2.z + hv.w * a2.w;
    }
    asrc[t] = s1;
    adst[t] = s2;
}

// ------------------------------------------------------------------
// per-edge leaky-relu logits, CSR order, layout [E][8]
__global__ void elog_kernel(const int* __restrict__ srcs, const int* __restrict__ dsts,
                            const float* __restrict__ asrc, const float* __restrict__ adst,
                            float* __restrict__ elog, int e) {
    int i = blockIdx.x * blockDim.x + threadIdx.x;
    if (i >= e) return;
    int s = srcs[i], d = dsts[i];
    float4 s0 = *(const float4*)(asrc + (size_t)s * 8);
    float4 s1 = *(const float4*)(asrc + (size_t)s * 8 + 4);
    float4 d0 = *(const float4*)(adst + (size_t)d * 8);
    float4 d1 = *(const float4*)(adst + (size_t)d * 8 + 4);
    float v[8] = {s0.x + d0.x, s0.y + d0.y, s0.z + d0.z, s0.w + d0.w,
                  s1.x + d1.x, s1.y + d1.y, s1.z + d1.z, s1.w + d1.w};
#pragma unroll
    for (int q = 0; q < 8; ++q) v[q] = v[q] > 0.f ? v[q] : NEG_SLOPE * v[q];
    *(float4*)(elog + (size_t)i * 8) = make_float4(v[0], v[1], v[2], v[3]);
    *(float4*)(elog + (size_t)i * 8 + 4) = make_float4(v[4], v[5], v[6], v[7]);
}

// ------------------------------------------------------------------
// one wave per dst node, two-pass softmax over precomputed elog:
//  pass 1: lanes = (edge-group 0..7) x (head 0..7), streaming elog, shfl reduce
//  pass 2: channel-parallel bf16 row gather, x8 unrolled
template <bool LAST>
__global__ __launch_bounds__(256) void gat_aggregate(
    const unsigned short* __restrict__ hb, const float* __restrict__ asrc,
    const float* __restrict__ adst, const int* __restrict__ row_ptr,
    const int* __restrict__ srcs, const float* __restrict__ elog,
    const float* __restrict__ bias, float* __restrict__ out,
    const void* __restrict__ batch, const int* __restrict__ mode,
    const float* __restrict__ lin_w, float* __restrict__ gsum,
    float* __restrict__ gcnt, int n) {
    int node = (int)((blockIdx.x * blockDim.x + threadIdx.x) >> 6);
    node = __builtin_amdgcn_readfirstlane(node);
    if (node >= n) return;
    const int lane = threadIdx.x & 63;
    const int h1 = lane & 7;       // pass-1 head
    const int eg = lane >> 3;      // pass-1 edge group
    const int head = lane >> 3;    // pass-2 head
    const int c0 = lane * 4;
    const int beg = row_ptr[node], end = row_ptr[node + 1];

    // ---------------- pass 1: per-head max & denom (streaming elog)
    float m = -1e30f, d = 0.f;
    for (int j = beg + eg; j < end; j += 8) {
        float e = elog[(size_t)j * 8 + h1];
        float nm = fmaxf(m, e);
        d = d * __expf(m - nm) + __expf(e - nm);
        m = nm;
    }
#pragma unroll
    for (int off = 8; off < 64; off <<= 1) {
        float mo = __shfl_xor(m, off, 64);
        float dd = __shfl_xor(d, off, 64);
        float nm = fmaxf(m, mo);
        d = d * __expf(m - nm) + dd * __expf(mo - nm);
        m = nm;
    }
    float mh = __shfl(m, head, 64);
    float dh = __shfl(d, head, 64);
    // fold in self-loop
    float adh = adst[node * 8 + head];
    float e0 = asrc[node * 8 + head] + adh;
    e0 = e0 > 0.f ? e0 : NEG_SLOPE * e0;
    float nm2 = fmaxf(mh, e0);
    dh = dh * __expf(mh - nm2) + __expf(e0 - nm2);
    mh = nm2;
    float invd = 1.f / (dh + 1e-16f);

    // ---------------- pass 2: weighted bf16 gather, 8 rows in flight
    float w0 = __expf(e0 - mh) * invd;
    ushort4 hv0 = *(const ushort4*)(hb + (size_t)node * HC + c0);
    float4 acc = make_float4(w0 * bf2f(hv0.x), w0 * bf2f(hv0.y),
                             w0 * bf2f(hv0.z), w0 * bf2f(hv0.w));
    int j = beg;
    for (; j + 8 <= end; j += 8) {
        int ss[8];
        ushort4 gv[8];
        float el[8];
#pragma unroll
        for (int q = 0; q < 8; ++q) ss[q] = srcs[j + q];
#pragma unroll
        for (int q = 0; q < 8; ++q) gv[q] = *(const ushort4*)(hb + (size_t)ss[q] * HC + c0);
#pragma unroll
        for (int q = 0; q < 8; ++q) el[q] = elog[(size_t)(j + q) * 8 + head];
#pragma unroll
        for (int q = 0; q < 8; ++q) {
            float w = __expf(el[q] - mh) * invd;
            acc.x = fmaf(w, bf2f(gv[q].x), acc.x);
            acc.y = fmaf(w, bf2f(gv[q].y), acc.y);
            acc.z = fmaf(w, bf2f(gv[q].z), acc.z);
            acc.w = fmaf(w, bf2f(gv[q].w), acc.w);
        }
    }
    for (; j < end; ++j) {
        int s = srcs[j];
        ushort4 g = *(const ushort4*)(hb + (size_t)s * HC + c0);
        float w = __expf(elog[(size_t)j * 8 + head] - mh) * invd;
        acc.x = fmaf(w, bf2f(g.x), acc.x);
        acc.y = fmaf(w, bf2f(g.y), acc.y);
        acc.z = fmaf(w, bf2f(g.z), acc.z);
        acc.w = fmaf(w, bf2f(g.w), acc.w);
    }

    float4 b = *(const float4*)(bias + c0);
    float o[4] = {acc.x + b.x, acc.y + b.y, acc.z + b.z, acc.w + b.w};
#pragma unroll
    for (int q = 0; q < 4; ++q) o[q] = o[q] > 0.f ? o[q] : __expf(o[q]) - 1.f;  // ELU
    if (!LAST) {
        *(float4*)(out + (size_t)node * HC + c0) = make_float4(o[0], o[1], o[2], o[3]);
    } else {
        float4 w = *(const float4*)(lin_w + c0);
        float s = o[0] * w.x + o[1] * w.y + o[2] * w.z + o[3] * w.w;
#pragma unroll
        for (int off = 32; off > 0; off >>= 1) s += __shfl_down(s, off, 64);
        if (lane == 0) {
            int g = IDX(batch, node, mode[0]);
            atomicAdd(&gsum[g], s);
            atomicAdd(&gcnt[g], 1.f);
        }
    }
}

__global__ void final_kernel(const float* __restrict__ gsum, const float* __restrict__ gcnt,
                             const float* __restrict__ lin_b, float* __restrict__ outp) {
    int g = blockIdx.x * blockDim.x + threadIdx.x;
    if (g >= GRAPHS) return;
    float c = gcnt[g];
    c = c > 1.f ? c : 1.f;
    outp[g] = gsum[g] / c + lin_b[0];
}

// ------------------------------------------------------------------
extern "C" void kernel_launch(void* const* d_in, const int* in_sizes, int n_in,
                              void* d_out, int out_size, void* d_ws, size_t ws_size,
                              hipStream_t stream) {
    const float* x = (const float*)d_in[0];
    const void* edge = d_in[1];
    const void* batch = d_in[2];
    const float* W[3]    = {(const float*)d_in[3], (const float*)d_in[7],  (const float*)d_in[11]};
    const float* ASRC[3] = {(const float*)d_in[4], (const float*)d_in[8],  (const float*)d_in[12]};
    const float* ADST[3] = {(const float*)d_in[5], (const float*)d_in[9],  (const float*)d_in[13]};
    const float* BIAS[3] = {(const float*)d_in[6], (const float*)d_in[10], (const float*)d_in[14]};
    const float* lin_w = (const float*)d_in[15];
    const float* lin_b = (const float*)d_in[16];
    float* outp = (float*)d_out;

    const int n = in_sizes[0] / 128;  // 50000
    const int e = in_sizes[1] / 2;    // 800000
    const int IN_CH = 128;

    char* ws = (char*)d_ws;
    size_t off = 0;
    auto alloc = [&](size_t bytes) -> void* {
        void* p = ws + off;
        off = (off + bytes + 255) & ~(size_t)255;
        return p;
    };
    float* hbuf   = (float*)alloc((size_t)n * HC * 4);
    float* gbuf   = (float*)alloc((size_t)n * HC * 4);
    unsigned short* hb16 = (unsigned short*)alloc((size_t)n * HC * 2);
    float* as_buf = (float*)alloc((size_t)n * HEADS * 4);
    float* ad_buf = (float*)alloc((size_t)n * HEADS * 4);
    int* hist     = (int*)alloc((size_t)n * 4);          // reused as fill
    int* row_ptr  = (int*)alloc((size_t)(n + 1) * 4);
    int* bsum     = (int*)alloc(1024);
    int* mode     = (int*)alloc(256);
    int* srcs     = (int*)alloc((size_t)e * 4);
    int* dsts     = (int*)alloc((size_t)e * 4);
    float* elog   = (float*)alloc((size_t)e * HEADS * 4);
    float* gsum   = (float*)alloc((size_t)GRAPHS * 4);
    float* gcnt   = (float*)alloc((size_t)GRAPHS * 4);
    if (off > ws_size) return;

    const int nb = (n + 255) / 256;

    detect_kernel<<<1, 256, 0, stream>>>((const unsigned int*)edge, mode, e);

    // CSR build
    hipMemsetAsync(hist, 0, (size_t)n * 4, stream);
    hist_kernel<<<(e + 255) / 256, 256, 0, stream>>>(edge, mode, hist, e);
    scan1<<<nb, 256, 0, stream>>>(hist, row_ptr, bsum, n);
    scan2<<<1, 256, 0, stream>>>(bsum, nb);
    scan3<<<nb, 256, 0, stream>>>(row_ptr, bsum, n, e);
    hipMemsetAsync(hist, 0, (size_t)n * 4, stream);
    scatter_kernel<<<(e + 255) / 256, 256, 0, stream>>>(edge, mode, row_ptr, hist, srcs, dsts, e);

    hipMemsetAsync(gsum, 0, (size_t)GRAPHS * 4, stream);
    hipMemsetAsync(gcnt, 0, (size_t)GRAPHS * 4, stream);

    dim3 gemm_grid((n + 127) / 128, 2);
    const float* cur_in = x;
    int K = IN_CH;
    for (int l = 0; l < 3; ++l) {
        gemm128<<<gemm_grid, 256, 0, stream>>>(cur_in, W[l], hbuf, hb16, n, K);
        alpha_kernel<<<(n * HEADS + 255) / 256, 256, 0, stream>>>(hbuf, ASRC[l], ADST[l],
                                                                  as_buf, ad_buf, n);
        elog_kernel<<<(e + 255) / 256, 256, 0, stream>>>(srcs, dsts, as_buf, ad_buf, elog, e);
        if (l < 2) {
            gat_aggregate<false><<<(n + 3) / 4, 256, 0, stream>>>(
                hb16, as_buf, ad_buf, row_ptr, srcs, elog, BIAS[l], gbuf,
                batch, mode, lin_w, gsum, gcnt, n);
        } else {
            gat_aggregate<true><<<(n + 3) / 4, 256, 0, stream>>>(
                hb16, as_buf, ad_buf, row_ptr, srcs, elog, BIAS[l], nullptr,
                batch, mode, lin_w, gsum, gcnt, n);
        }
        cur_in = gbuf;
        K = HC;
    }

    final_kernel<<<2, 256, 0, stream>>>(gsum, gcnt, lin_b, outp);
}